// Round 1
// baseline (420.641 us; speedup 1.0000x reference)
//
#include <hip/hip_runtime.h>
#include <cstdint>
#include <cstddef>

// Model dims
#define VOCABSZ 400001
#define Hn 100      // hidden
#define Tn 25       // timesteps
#define Bn 512      // batch
#define FCn 128
#define Rr 4        // rows (batch elems) per block
#define NBLK (Bn / Rr)   // 128 blocks
#define NTHR 512

typedef _Float16 half2_t __attribute__((ext_vector_type(2)));

__device__ __forceinline__ half2_t h2bits(unsigned v) {
    union { unsigned u; half2_t h; } x; x.u = v; return x.h;
}
__device__ __forceinline__ float fdot2f(half2_t a, half2_t b, float c) {
    // v_dot2_f32_f16: fp16 multiply, fp32 accumulate
    return __builtin_amdgcn_fdot2(a, b, c, false);
}
__device__ __forceinline__ float sigm(float x) {
    return __fdividef(1.0f, 1.0f + __expf(-x));
}
__device__ __forceinline__ float tanh_fast(float x) {
    float e = __expf(2.0f * x);
    return __fdividef(e - 1.0f, e + 1.0f);
}

// ---------------------------------------------------------------------------
// Prep: repack k1,k2 (fp32 [200][400], gate order i,j,f,o along columns) into
// fp16 half2 layout [kp][u][type] where kp = k/2 pairs along the reduction dim:
//   KL[kp*400 + u*4 + type] = { k[2kp][type*100+u], k[2kp+1][type*100+u] }
// so a thread owning unit u reads one 16B uint4 = 4 gates x 2 k's per kp.
// ---------------------------------------------------------------------------
__global__ void prep_weights(const float* __restrict__ k1,
                             const float* __restrict__ k2,
                             half2_t* __restrict__ K1L,
                             half2_t* __restrict__ K2L) {
    int t = blockIdx.x * blockDim.x + threadIdx.x;
    if (t >= 80000) return;            // 2 matrices x 40000 half2 each
    int m = t / 40000;
    int p = t % 40000;
    int kp   = p / 400;                // 0..99
    int rem  = p % 400;
    int u    = rem >> 2;               // 0..99
    int type = rem & 3;                // i,j,f,o
    const float* src = m ? k2 : k1;
    int g = type * 100 + u;
    float a0 = src[(2 * kp) * 400 + g];
    float a1 = src[(2 * kp + 1) * 400 + g];
    half2_t h;
    h.x = (_Float16)a0;
    h.y = (_Float16)a1;
    (m ? K2L : K1L)[p] = h;
}

// ---------------------------------------------------------------------------
// Main: one block handles Rr=4 batch rows through all 25 steps + FC head.
// K1 (both x-part and h-part) lives in LDS (160,000 B fp16). K2 is read from
// L2 (fp16). Thread t<400: u=t>>2 (hidden unit), r=t&3 (row) -> owns all 4
// gates of (r,u); cell state c1,c2 in registers; h broadcast via small LDS.
// ---------------------------------------------------------------------------
__global__ __launch_bounds__(NTHR, 1) void lstm_main(
    const int*   __restrict__ features,   // [B][T]
    const float* __restrict__ embedding,  // [VOCAB][H]
    const float* __restrict__ b1,         // [400]
    const float* __restrict__ b2,         // [400]
    const float* __restrict__ w_fc1,      // [100][128]
    const float* __restrict__ b_fc1,      // [128]
    const float* __restrict__ w_fc2,      // [128][2]
    const float* __restrict__ b_fc2,      // [2]
    const uint4* __restrict__ K1Lg,       // 10000 uint4 (fp16 packed)
    const uint4* __restrict__ K2Lg,       // 10000 uint4
    float*       __restrict__ out)        // [B][2]
{
    __shared__ uint4   ldsK1[10000];      // 160,000 B
    __shared__ half2_t xbuf[Rr][50];      // x_t per row, fp16 pairs
    __shared__ half2_t h1buf[Rr][50];
    __shared__ half2_t h2buf[Rr][50];
    __shared__ float   wred[8][2];

    const int tid = threadIdx.x;

    // Stage K1 fp16 into LDS (coalesced 16B copies)
    for (int i = tid; i < 10000; i += NTHR) ldsK1[i] = K1Lg[i];

    // Zero initial hidden states
    if (tid < Rr * 50) {
        half2_t z; z.x = (_Float16)0.0f; z.y = (_Float16)0.0f;
        ((half2_t*)h1buf)[tid] = z;
        ((half2_t*)h2buf)[tid] = z;
    }

    const int u = tid >> 2;          // hidden unit
    const int r = tid & 3;           // row within block
    const bool active = (u < Hn);

    float c1 = 0.0f, c2 = 0.0f;
    float b1v[4], b2v[4];
    if (active) {
        #pragma unroll
        for (int ty = 0; ty < 4; ty++) {
            b1v[ty] = b1[ty * 100 + u];
            b2v[ty] = b2[ty * 100 + u];
        }
    }

    // Embedding prefetch for step 0 (threads 0..199: rr=t/50, kp=t%50)
    float2 xpre = {0.0f, 0.0f};
    if (tid < Rr * 50) {
        int rr = tid / 50, kp = tid % 50;
        int f0 = features[(blockIdx.x * Rr + rr) * Tn + 0];
        xpre = *(const float2*)(embedding + (size_t)f0 * Hn + 2 * kp);
    }
    __syncthreads();

    for (int step = 0; step < Tn; step++) {
        // publish prefetched x_t
        if (tid < Rr * 50) {
            int rr = tid / 50, kp = tid % 50;
            half2_t h; h.x = (_Float16)xpre.x; h.y = (_Float16)xpre.y;
            xbuf[rr][kp] = h;
        }
        __syncthreads();                          // B1: xbuf ready

        // prefetch next step's embedding rows (latency hidden by dots)
        if (tid < Rr * 50 && step + 1 < Tn) {
            int rr = tid / 50, kp = tid % 50;
            int f1 = features[(blockIdx.x * Rr + rr) * Tn + step + 1];
            xpre = *(const float2*)(embedding + (size_t)f1 * Hn + 2 * kp);
        }

        float a0, a1, a2, a3;
        if (active) {
            a0 = b1v[0]; a1 = b1v[1]; a2 = b1v[2]; a3 = b1v[3];
            // layer-1 x-part: k = 0..99 (kp 0..49), weights from LDS
            #pragma unroll
            for (int kp = 0; kp < 50; kp++) {
                uint4 w = ldsK1[kp * 100 + u];
                half2_t xv = xbuf[r][kp];
                a0 = fdot2f(h2bits(w.x), xv, a0);
                a1 = fdot2f(h2bits(w.y), xv, a1);
                a2 = fdot2f(h2bits(w.z), xv, a2);
                a3 = fdot2f(h2bits(w.w), xv, a3);
            }
            // layer-1 h-part: k = 100..199 (kp 50..99)
            #pragma unroll
            for (int kp = 0; kp < 50; kp++) {
                uint4 w = ldsK1[(50 + kp) * 100 + u];
                half2_t hv = h1buf[r][kp];
                a0 = fdot2f(h2bits(w.x), hv, a0);
                a1 = fdot2f(h2bits(w.y), hv, a1);
                a2 = fdot2f(h2bits(w.z), hv, a2);
                a3 = fdot2f(h2bits(w.w), hv, a3);
            }
        }
        __syncthreads();                          // B2: h1buf(old) reads done
        if (active) {
            float ig = sigm(a0);
            float jg = tanh_fast(a1);
            float fg = sigm(a2 + 1.0f);           // forget_bias = 1.0
            float og = sigm(a3);
            c1 = c1 * fg + ig * jg;
            float h1n = tanh_fast(c1) * og;
            ((_Float16*)h1buf)[r * 100 + u] = (_Float16)h1n;
        }
        __syncthreads();                          // B3: h1buf(new) visible

        if (active) {
            a0 = b2v[0]; a1 = b2v[1]; a2 = b2v[2]; a3 = b2v[3];
            // layer-2 x-part = h1(new), weights from L2 (fp16)
            #pragma unroll 10
            for (int kp = 0; kp < 50; kp++) {
                uint4 w = K2Lg[kp * 100 + u];
                half2_t hv = h1buf[r][kp];
                a0 = fdot2f(h2bits(w.x), hv, a0);
                a1 = fdot2f(h2bits(w.y), hv, a1);
                a2 = fdot2f(h2bits(w.z), hv, a2);
                a3 = fdot2f(h2bits(w.w), hv, a3);
            }
            // layer-2 h-part = h2(old)
            #pragma unroll 10
            for (int kp = 0; kp < 50; kp++) {
                uint4 w = K2Lg[(50 + kp) * 100 + u];
                half2_t hv = h2buf[r][kp];
                a0 = fdot2f(h2bits(w.x), hv, a0);
                a1 = fdot2f(h2bits(w.y), hv, a1);
                a2 = fdot2f(h2bits(w.z), hv, a2);
                a3 = fdot2f(h2bits(w.w), hv, a3);
            }
        }
        __syncthreads();                          // B4: h2buf(old) reads done
        if (active) {
            float ig = sigm(a0);
            float jg = tanh_fast(a1);
            float fg = sigm(a2 + 1.0f);
            float og = sigm(a3);
            c2 = c2 * fg + ig * jg;
            float h2n = tanh_fast(c2) * og;
            ((_Float16*)h2buf)[r * 100 + u] = (_Float16)h2n;
        }
    }
    __syncthreads();

    // FC head: pred = (h2 @ w_fc1 + b_fc1) @ w_fc2 + b_fc2
    // thread t = r2*128 + j; all 512 threads active
    {
        int r2 = tid >> 7;
        int j  = tid & 127;
        const _Float16* h2p = (const _Float16*)h2buf + r2 * 100;
        float acc = b_fc1[j];
        #pragma unroll 10
        for (int uu = 0; uu < Hn; uu++)
            acc = fmaf((float)h2p[uu], w_fc1[uu * FCn + j], acc);
        float p0 = acc * w_fc2[2 * j + 0];
        float p1 = acc * w_fc2[2 * j + 1];
        #pragma unroll
        for (int off = 32; off > 0; off >>= 1) {
            p0 += __shfl_down(p0, off, 64);
            p1 += __shfl_down(p1, off, 64);
        }
        if ((tid & 63) == 0) {
            int w = tid >> 6;                     // wave -> row: r2 = w/2
            wred[w][0] = p0;
            wred[w][1] = p1;
        }
    }
    __syncthreads();
    if (tid < 8) {
        int rr = tid >> 1, cls = tid & 1;
        out[(blockIdx.x * Rr + rr) * 2 + cls] =
            wred[2 * rr][cls] + wred[2 * rr + 1][cls] + b_fc2[cls];
    }
}

extern "C" void kernel_launch(void* const* d_in, const int* in_sizes, int n_in,
                              void* d_out, int out_size, void* d_ws, size_t ws_size,
                              hipStream_t stream) {
    const int*   features  = (const int*)  d_in[0];
    const float* embedding = (const float*)d_in[1];
    const float* k1        = (const float*)d_in[2];
    const float* b1        = (const float*)d_in[3];
    const float* k2        = (const float*)d_in[4];
    const float* b2        = (const float*)d_in[5];
    const float* w_fc1     = (const float*)d_in[6];
    const float* b_fc1     = (const float*)d_in[7];
    const float* w_fc2     = (const float*)d_in[8];
    const float* b_fc2     = (const float*)d_in[9];

    half2_t* K1L = (half2_t*)d_ws;                         // 160,000 B
    half2_t* K2L = (half2_t*)((char*)d_ws + 160000);       // 160,000 B

    prep_weights<<<(80000 + 255) / 256, 256, 0, stream>>>(k1, k2, K1L, K2L);
    lstm_main<<<NBLK, NTHR, 0, stream>>>(features, embedding, b1, b2,
                                         w_fc1, b_fc1, w_fc2, b_fc2,
                                         (const uint4*)K1L, (const uint4*)K2L,
                                         (float*)d_out);
}

// Round 3
// 344.095 us; speedup vs baseline: 1.2225x; 1.2225x over previous
//
#include <hip/hip_runtime.h>
#include <cstdint>
#include <cstddef>

// Model dims
#define VOCABSZ 400001
#define Hn 100      // hidden
#define Tn 25       // timesteps
#define Bn 512      // batch
#define FCn 128
#define Rr 2        // rows (batch elems) per block
#define NBLK (Bn / Rr)   // 256 blocks -> all 256 CUs
#define NTHR 512

typedef _Float16 half2_t __attribute__((ext_vector_type(2)));

__device__ __forceinline__ half2_t h2bits(unsigned v) {
    union { unsigned u; half2_t h; } x; x.u = v; return x.h;
}
__device__ __forceinline__ float fdot2f(half2_t a, half2_t b, float c) {
    return __builtin_amdgcn_fdot2(a, b, c, false);   // v_dot2_f32_f16
}
__device__ __forceinline__ float sigm(float x) {
    return __fdividef(1.0f, 1.0f + __expf(-x));
}
__device__ __forceinline__ float tanh_fast(float x) {
    float e = __expf(2.0f * x);
    return __fdividef(e - 1.0f, e + 1.0f);
}

// ---------------------------------------------------------------------------
// Prep: repack k1,k2 (fp32 [200][400], columns c = g*100+u, gates i,j,f,o)
// into fp16 chunk layout WP[l][kq][o] (uint4), o = 4u+g owning column c.
// Chunk kq covers k = 8kq..8kq+7; dword j = fp16 pair (k=8kq+2j, 8kq+2j+1).
// Matches the x-side layout: LDS xh row read as uint4 by lane kq.
// ---------------------------------------------------------------------------
__global__ void prep_weights(const float* __restrict__ k1,
                             const float* __restrict__ k2,
                             uint4* __restrict__ WP) {
    int t = blockIdx.x * blockDim.x + threadIdx.x;
    if (t >= 2 * 25 * 400) return;
    int l   = t / 10000;
    int rem = t % 10000;
    int kq  = rem / 400;
    int o   = rem % 400;
    int u = o >> 2, g = o & 3;
    int c = g * 100 + u;
    const float* K = l ? k2 : k1;
    union { unsigned u32; half2_t h; } d[4];
    #pragma unroll
    for (int j = 0; j < 4; j++) {
        int k0 = 8 * kq + 2 * j;
        d[j].h.x = (_Float16)K[(k0    ) * 400 + c];
        d[j].h.y = (_Float16)K[(k0 + 1) * 400 + c];
    }
    uint4 v; v.x = d[0].u32; v.y = d[1].u32; v.z = d[2].u32; v.w = d[3].u32;
    WP[t] = v;
}

// Gate exchange within the quad (o = 4u+g) + LSTM cell update.
// All 4 lanes of the quad end up with the same c,h (redundant, cheap).
__device__ __forceinline__ float lstm_update(float z, int g, float& cst) {
    float t1 = __shfl_xor(z, 1);
    float t2 = __shfl_xor(z, 2);
    float t3 = __shfl_xor(t1, 2);
    bool g0 = (g & 1) != 0, g1 = (g & 2) != 0;
    float vi = g1 ? (g0 ? t3 : t2) : (g0 ? t1 : z);
    float vj = g1 ? (g0 ? t2 : t3) : (g0 ? z  : t1);
    float vf = g1 ? (g0 ? t1 : z ) : (g0 ? t3 : t2);
    float vo = g1 ? (g0 ? z  : t1) : (g0 ? t2 : t3);
    cst = cst * sigm(vf + 1.0f) + sigm(vi) * tanh_fast(vj);   // forget_bias=1
    return tanh_fast(cst) * sigm(vo);
}

// One gemv for both rows: weights from regs (w[LIDX][*]), x from LDS row
// loaded once per wave (lanes 0-24 = 25 x 16B chunks), broadcast to the
// whole wave via v_readlane -> SGPR operand of v_dot2_f32_f16.
// MUST be executed with all 64 lanes of the wave enabled (wave-uniform
// guard only!) — readlane ignores exec, so lanes 0-24 must have loaded.
#define GEMV_LAYER(SRC0, SRC1, LIDX, BIAS, Z0, Z1)                           \
  {                                                                          \
    const uint4* _p0 = (const uint4*)(SRC0);                                 \
    const uint4* _p1 = (const uint4*)(SRC1);                                 \
    uint4 _vx = _p0[lane < 25 ? lane : 0];                                   \
    uint4 _vy = _p1[lane < 25 ? lane : 0];                                   \
    float _a0=0.f,_a1=0.f,_a2=0.f,_a3=0.f;                                   \
    float _d0=0.f,_d1=0.f,_d2=0.f,_d3=0.f;                                   \
    _Pragma("unroll")                                                        \
    for (int kq = 0; kq < 25; kq++) {                                        \
      uint4 _w = w[LIDX][kq];                                                \
      unsigned _s0 = (unsigned)__builtin_amdgcn_readlane((int)_vx.x, kq);    \
      unsigned _s1 = (unsigned)__builtin_amdgcn_readlane((int)_vx.y, kq);    \
      unsigned _s2 = (unsigned)__builtin_amdgcn_readlane((int)_vx.z, kq);    \
      unsigned _s3 = (unsigned)__builtin_amdgcn_readlane((int)_vx.w, kq);    \
      _a0 = fdot2f(h2bits(_w.x), h2bits(_s0), _a0);                          \
      _a1 = fdot2f(h2bits(_w.y), h2bits(_s1), _a1);                          \
      _a2 = fdot2f(h2bits(_w.z), h2bits(_s2), _a2);                          \
      _a3 = fdot2f(h2bits(_w.w), h2bits(_s3), _a3);                          \
      unsigned _t0 = (unsigned)__builtin_amdgcn_readlane((int)_vy.x, kq);    \
      unsigned _t1 = (unsigned)__builtin_amdgcn_readlane((int)_vy.y, kq);    \
      unsigned _t2 = (unsigned)__builtin_amdgcn_readlane((int)_vy.z, kq);    \
      unsigned _t3 = (unsigned)__builtin_amdgcn_readlane((int)_vy.w, kq);    \
      _d0 = fdot2f(h2bits(_w.x), h2bits(_t0), _d0);                          \
      _d1 = fdot2f(h2bits(_w.y), h2bits(_t1), _d1);                          \
      _d2 = fdot2f(h2bits(_w.z), h2bits(_t2), _d2);                          \
      _d3 = fdot2f(h2bits(_w.w), h2bits(_t3), _d3);                          \
    }                                                                        \
    Z0 = _a0 + _a1 + _a2 + _a3 + (BIAS);                                     \
    Z1 = _d0 + _d1 + _d2 + _d3 + (BIAS);                                     \
  }

__global__ __launch_bounds__(NTHR, 2) void lstm_main(
    const int*   __restrict__ features,   // [B][T]
    const float* __restrict__ embedding,  // [VOCAB][H]
    const float* __restrict__ b1,         // [400]
    const float* __restrict__ b2,         // [400]
    const float* __restrict__ w_fc1,      // [100][128]
    const float* __restrict__ b_fc1,      // [128]
    const float* __restrict__ w_fc2,      // [128][2]
    const float* __restrict__ b_fc2,      // [2]
    const uint4* __restrict__ WP,         // [2][25][400] fp16 chunks
    float*       __restrict__ out)        // [B][2]
{
    __shared__ _Float16 xh1[Rr][200];     // [x(100) | h1(100)] per row
    __shared__ _Float16 xh2[Rr][200];     // [h1(100) | h2(100)] per row
    __shared__ float    wred[8][2];

    const int tid  = threadIdx.x;
    const int lane = tid & 63;
    const int o    = (tid < 400) ? tid : 399;   // clamp for uniform loads
    const int u = o >> 2, g = o & 3;
    const int c = g * 100 + u;
    const bool owner = (tid < 400);       // owns a real column (may write)
    // waves 0..6 (tid < 448) run the gemv with FULL exec so lanes 0-24
    // always execute the LDS loads that feed v_readlane.

    // Both layers' weight columns -> 200 VGPRs (2 x 25 uint4), loaded once.
    uint4 w[2][25];
    #pragma unroll
    for (int l = 0; l < 2; l++)
        #pragma unroll
        for (int kq = 0; kq < 25; kq++)
            w[l][kq] = WP[(l * 25 + kq) * 400 + o];

    const float bias1 = b1[c];
    const float bias2 = b2[c];

    // Init LDS: zero h-parts; stage x(0) as fp16.
    if (tid < 200) {
        int r = tid / 100, uu = tid % 100;
        xh1[r][100 + uu] = (_Float16)0.0f;
        xh2[r][uu]       = (_Float16)0.0f;
        xh2[r][100 + uu] = (_Float16)0.0f;
    }
    if (tid < 100) {
        int r = tid / 50, p = tid % 50;
        int f0 = features[(blockIdx.x * Rr + r) * Tn + 0];
        float2 e = *(const float2*)(embedding + (size_t)f0 * Hn + 2 * p);
        half2_t h; h.x = (_Float16)e.x; h.y = (_Float16)e.y;
        ((half2_t*)&xh1[r][0])[p] = h;
    }
    __syncthreads();

    float c1[Rr] = {0.f, 0.f}, c2[Rr] = {0.f, 0.f};
    float h1v[Rr] = {0.f, 0.f}, h2v[Rr] = {0.f, 0.f};

    for (int step = 0; step < Tn; step++) {
        float2 epre = {0.f, 0.f};
        int prow = 0, pp = 0;
        if (tid < 448) {                      // wave-uniform: waves 0..6
            // x(t+1) prefetch: the 100 owner g==1 threads cover 2 rows x 50 half2.
            if (owner && g == 1 && step + 1 < Tn) {
                prow = (u >= 50);
                pp   = u % 50;
                int f1 = features[(blockIdx.x * Rr + prow) * Tn + step + 1];
                epre = *(const float2*)(embedding + (size_t)f1 * Hn + 2 * pp);
            }
            float z0, z1;
            GEMV_LAYER(&xh1[0][0], &xh1[1][0], 0, bias1, z0, z1);
            h1v[0] = lstm_update(z0, g, c1[0]);
            h1v[1] = lstm_update(z1, g, c1[1]);
        }
        __syncthreads();                      // B1: xh1/xh2 reads done
        if (owner) {
            if (g == 0) {                     // h1 -> recurrent + layer2 input
                xh1[0][100 + u] = (_Float16)h1v[0];
                xh1[1][100 + u] = (_Float16)h1v[1];
                xh2[0][u]       = (_Float16)h1v[0];
                xh2[1][u]       = (_Float16)h1v[1];
            }
            if (g == 1 && step + 1 < Tn) {    // publish x(t+1)
                half2_t h; h.x = (_Float16)epre.x; h.y = (_Float16)epre.y;
                ((half2_t*)&xh1[prow][0])[pp] = h;
            }
        }
        __syncthreads();                      // B2: h1/x published
        if (tid < 448) {                      // wave-uniform: waves 0..6
            float z0, z1;
            GEMV_LAYER(&xh2[0][0], &xh2[1][0], 1, bias2, z0, z1);
            h2v[0] = lstm_update(z0, g, c2[0]);
            h2v[1] = lstm_update(z1, g, c2[1]);
        }
        __syncthreads();                      // B3: xh2 reads done
        if (owner && g == 0) {
            xh2[0][100 + u] = (_Float16)h2v[0];
            xh2[1][100 + u] = (_Float16)h2v[1];
        }
        // no 4th barrier needed: next gemv1 doesn't touch xh2, and the next
        // writes to xh2 happen only after the next B1/B2.
    }
    __syncthreads();                          // final h2 visible

    // FC head: pred = (h2 @ w_fc1 + b_fc1) @ w_fc2 + b_fc2
    if (tid < Rr * FCn) {                     // 256 threads: (r,j)
        int r = tid >> 7;
        int j = tid & 127;
        float acc = b_fc1[j];
        #pragma unroll 10
        for (int uu = 0; uu < Hn; uu++)
            acc = fmaf((float)xh2[r][100 + uu], w_fc1[uu * FCn + j], acc);
        float p0 = acc * w_fc2[2 * j + 0];
        float p1 = acc * w_fc2[2 * j + 1];
        #pragma unroll
        for (int off = 32; off > 0; off >>= 1) {
            p0 += __shfl_down(p0, off, 64);
            p1 += __shfl_down(p1, off, 64);
        }
        if (lane == 0) {                      // waves 0..3
            int wv = tid >> 6;
            wred[wv][0] = p0;
            wred[wv][1] = p1;
        }
    }
    __syncthreads();
    if (tid < 4) {
        int r = tid >> 1, cls = tid & 1;
        out[(blockIdx.x * Rr + r) * 2 + cls] =
            wred[2 * r][cls] + wred[2 * r + 1][cls] + b_fc2[cls];
    }
}

extern "C" void kernel_launch(void* const* d_in, const int* in_sizes, int n_in,
                              void* d_out, int out_size, void* d_ws, size_t ws_size,
                              hipStream_t stream) {
    const int*   features  = (const int*)  d_in[0];
    const float* embedding = (const float*)d_in[1];
    const float* k1        = (const float*)d_in[2];
    const float* b1        = (const float*)d_in[3];
    const float* k2        = (const float*)d_in[4];
    const float* b2        = (const float*)d_in[5];
    const float* w_fc1     = (const float*)d_in[6];
    const float* b_fc1     = (const float*)d_in[7];
    const float* w_fc2     = (const float*)d_in[8];
    const float* b_fc2     = (const float*)d_in[9];

    uint4* WP = (uint4*)d_ws;                 // 2*25*400*16 = 320,000 B

    prep_weights<<<(20000 + 255) / 256, 256, 0, stream>>>(k1, k2, WP);
    lstm_main<<<NBLK, NTHR, 0, stream>>>(features, embedding, b1, b2,
                                         w_fc1, b_fc1, w_fc2, b_fc2,
                                         WP, (float*)d_out);
}